// Round 8
// baseline (255.653 us; speedup 1.0000x reference)
//
#include <hip/hip_runtime.h>

typedef __attribute__((ext_vector_type(4)))  float          f32x4;
typedef __attribute__((ext_vector_type(16))) float          f32x16;
typedef __attribute__((ext_vector_type(8)))  short          s16x8;
typedef __attribute__((ext_vector_type(4)))  unsigned short u16x4;
typedef __attribute__((ext_vector_type(8)))  unsigned short u16x8;

#define MFMA_BF16(a, b, c) __builtin_amdgcn_mfma_f32_16x16x32_bf16((a), (b), (c), 0, 0, 0)
#define MFMA32(a, b, c)    __builtin_amdgcn_mfma_f32_32x32x16_bf16((a), (b), (c), 0, 0, 0)

static constexpr int Bb = 2, Ss = 2048, Ee = 1024, Hh = 16, Dd = 64;
static constexpr size_t M4 = 4u * 1024 * 1024;
static constexpr size_t M1 = 1024 * 1024;

__device__ __forceinline__ unsigned short f2b(float f) {
    unsigned u = __builtin_bit_cast(unsigned, f);
    u += 0x7fffu + ((u >> 16) & 1u);
    return (unsigned short)(u >> 16);
}

__device__ __forceinline__ void gld_lds16(const unsigned short* g, unsigned short* l) {
    __builtin_amdgcn_global_load_lds(
        (const __attribute__((address_space(1))) unsigned int*)g,
        (__attribute__((address_space(3))) unsigned int*)l, 16, 0, 0);
}

// ---------------------------------------------------------------------------
// Convert fp32 inputs to bf16 workspace + mask -> float array. (FROZEN)
// ---------------------------------------------------------------------------
struct CvtArgs { const float* src[7]; unsigned short* dst;
                 const int* mask; float* maskf; };

__global__ __launch_bounds__(256) void cvt_bf16(CvtArgs a)
{
    if (blockIdx.x == 8192) { // mask -> float (4096 elems)
#pragma unroll
        for (int j = 0; j < 16; j++) {
            int idx = threadIdx.x + j * 256;
            a.maskf[idx] = a.mask[idx] ? 1.f : 0.f;
        }
        return;
    }
    size_t i = ((size_t)blockIdx.x * 256 + threadIdx.x) * 8;
    int seg; size_t off;
    if (i < 3 * M4) { seg = (int)(i / M4);     off = i % M4; }
    else            { size_t j = i - 3 * M4;
                      seg = 3 + (int)(j / M1); off = j % M1; }
    const float* s = a.src[seg] + off;
    f32x4 x0 = *(const f32x4*)s;
    f32x4 x1 = *(const f32x4*)(s + 4);
    u16x8 o = (u16x8){f2b(x0[0]), f2b(x0[1]), f2b(x0[2]), f2b(x0[3]),
                      f2b(x1[0]), f2b(x1[1]), f2b(x1[2]), f2b(x1[3])};
    *(u16x8*)(a.dst + i) = o;
}

// ---------------------------------------------------------------------------
// bf16 GEMM body, 128x128 tile, BK=64 as two independent [row][32] halves:
// 8 back-to-back global_load_lds then ONE vmcnt drain + barrier per 64-k
// (was: two drains per 64-k at BK=32). LDS addressing within each half is
// byte-identical to the measured m97 layout (same bank behavior); af/bf
// registers reused across the kk sub-loop (no VGPR growth). 16 K-iters.
// OUT_MODE: 1 bf16 [m][n]; 2 bf16 V-transposed; 3 bf16 scaled by
// 0.125*log2(e) (Q path: folds attn scale + exp->exp2 conversion).
// ---------------------------------------------------------------------------
template <int OUT_MODE>
__device__ __forceinline__ void gemm_bf16_body(const unsigned short* __restrict__ A,
                                               const unsigned short* __restrict__ W,
                                               const float* __restrict__ bias,
                                               void* __restrict__ Cv,
                                               int m0, int n0)
{
    __shared__ __align__(16) unsigned short Al[2][128 * 32];
    __shared__ __align__(16) unsigned short Bl[2][128 * 32];

    const int tid  = threadIdx.x;
    const int lane = tid & 63;
    const int wid  = tid >> 6;
    const int quad = lane >> 4;
    const int lr   = lane & 15;
    const int wr   = (wid >> 1) * 64;
    const int wc   = (wid & 1) * 64;

    const int srow = wid * 32 + (lane >> 2);
    const int sk8  = (lane & 3) * 8;
    const unsigned short* gA = A + (size_t)(m0 + srow) * 1024 + sk8;
    const unsigned short* gW = W + (size_t)(n0 + srow) * 1024 + sk8;
    const int swid = wid * 1024;

    f32x4 acc[4][4];
#pragma unroll
    for (int i = 0; i < 4; i++)
#pragma unroll
        for (int j = 0; j < 4; j++) acc[i][j] = (f32x4){0.f, 0.f, 0.f, 0.f};

    for (int ks = 0; ks < 1024; ks += 64) {
        __syncthreads();
        gld_lds16(gA + ks,                  &Al[0][swid]);
        gld_lds16(gA + ks + 16 * 1024,      &Al[0][swid + 512]);
        gld_lds16(gA + ks + 32,             &Al[1][swid]);
        gld_lds16(gA + ks + 32 + 16 * 1024, &Al[1][swid + 512]);
        gld_lds16(gW + ks,                  &Bl[0][swid]);
        gld_lds16(gW + ks + 16 * 1024,      &Bl[0][swid + 512]);
        gld_lds16(gW + ks + 32,             &Bl[1][swid]);
        gld_lds16(gW + ks + 32 + 16 * 1024, &Bl[1][swid + 512]);
        __syncthreads();

#pragma unroll
        for (int kk = 0; kk < 2; kk++) {
            s16x8 af[4], bf[4];
#pragma unroll
            for (int t = 0; t < 4; t++) {
                af[t] = *(const s16x8*)&Al[kk][(wr + t * 16 + lr) * 32 + quad * 8];
                bf[t] = *(const s16x8*)&Bl[kk][(wc + t * 16 + lr) * 32 + quad * 8];
            }
#pragma unroll
            for (int mt = 0; mt < 4; mt++)
#pragma unroll
                for (int nt = 0; nt < 4; nt++)
                    acc[mt][nt] = MFMA_BF16(af[mt], bf[nt], acc[mt][nt]);
        }
    }

#pragma unroll
    for (int mt = 0; mt < 4; mt++)
#pragma unroll
        for (int nt = 0; nt < 4; nt++) {
            int   col  = n0 + wc + nt * 16 + lr;
            float bcol = bias[col];
            int   rbase = m0 + wr + mt * 16 + quad * 4;
            if (OUT_MODE == 2) {
                int bb = rbase >> 11, s = rbase & 2047;
                u16x4 pk;
#pragma unroll
                for (int r = 0; r < 4; r++) pk[r] = f2b(acc[mt][nt][r] + bcol);
                *(u16x4*)&((unsigned short*)Cv)[((size_t)(bb * 1024 + col)) * 2048 + s] = pk;
            } else {
#pragma unroll
                for (int r = 0; r < 4; r++) {
                    float v = acc[mt][nt][r] + bcol;
                    if (OUT_MODE == 3) v *= 0.180336884f; // 0.125 * log2(e)
                    ((unsigned short*)Cv)[(size_t)(rbase + r) * 1024 + col] = f2b(v);
                }
            }
        }
}

struct GArgs {
    const unsigned short* A[3];
    const unsigned short* W[3];
    const float* bias[3];
    unsigned short* C[3];
};

// XCD-band swizzle: 1D grid 768. xcd = id&7 owns a 512-row A-band for ALL
// n-tiles and all z; dispatch rounds (32 blocks/XCD each) serialize z, so the
// per-XCD L2 working set is 1 MB A-band + 2 MB W = 3 MB < 4 MiB.
__global__ __launch_bounds__(256) void proj_gemm(GArgs ga)
{
    const int id  = blockIdx.x;
    const int xcd = id & 7;
    const int t   = id >> 3;        // 0..95
    const int z   = t >> 5;         // one z per dispatch round
    const int tt  = t & 31;
    const int n0  = (tt & 7) * 128;
    const int m0  = (xcd * 4 + (tt >> 3)) * 128;

    if (z == 2)      gemm_bf16_body<2>(ga.A[2], ga.W[2], ga.bias[2], ga.C[2], m0, n0);
    else if (z == 1) gemm_bf16_body<1>(ga.A[1], ga.W[1], ga.bias[1], ga.C[1], m0, n0);
    else             gemm_bf16_body<3>(ga.A[0], ga.W[0], ga.bias[0], ga.C[0], m0, n0);
}

// ---------------------------------------------------------------------------
// out GEMM: 128x64 tiles -> grid 512 (2 blocks/CU), XCD band swizzle.
// Same BK=64 two-half scheme (6 gld + one drain per 64-k). LDS 24 KB.
// ---------------------------------------------------------------------------
__global__ __launch_bounds__(256)
void out_gemm(const unsigned short* __restrict__ A,
              const unsigned short* __restrict__ W,
              const float* __restrict__ bias,
              float* __restrict__ C)
{
    __shared__ __align__(16) unsigned short Al[2][128 * 32];
    __shared__ __align__(16) unsigned short Bl[2][64 * 32];

    const int id  = blockIdx.x;
    const int xcd = id & 7;
    const int t   = id >> 3;            // 0..63
    const int n0  = (t & 15) * 64;
    const int m0  = (xcd * 4 + (t >> 4)) * 128;

    const int tid  = threadIdx.x;
    const int lane = tid & 63;
    const int wid  = tid >> 6;
    const int quad = lane >> 4;
    const int lr   = lane & 15;
    const int wr   = (wid >> 1) * 64;
    const int wc   = (wid & 1) * 32;

    const int srowA = wid * 32 + (lane >> 2);
    const int srowW = wid * 16 + (lane >> 2);
    const int sk8   = (lane & 3) * 8;
    const unsigned short* gA = A + (size_t)(m0 + srowA) * 1024 + sk8;
    const unsigned short* gW = W + (size_t)(n0 + srowW) * 1024 + sk8;
    const int swidA = wid * 1024;
    const int swidW = wid * 512;

    f32x4 acc[4][2];
#pragma unroll
    for (int i = 0; i < 4; i++)
#pragma unroll
        for (int j = 0; j < 2; j++) acc[i][j] = (f32x4){0.f, 0.f, 0.f, 0.f};

    for (int ks = 0; ks < 1024; ks += 64) {
        __syncthreads();
        gld_lds16(gA + ks,                  &Al[0][swidA]);
        gld_lds16(gA + ks + 16 * 1024,      &Al[0][swidA + 512]);
        gld_lds16(gA + ks + 32,             &Al[1][swidA]);
        gld_lds16(gA + ks + 32 + 16 * 1024, &Al[1][swidA + 512]);
        gld_lds16(gW + ks,                  &Bl[0][swidW]);
        gld_lds16(gW + ks + 32,             &Bl[1][swidW]);
        __syncthreads();

#pragma unroll
        for (int kk = 0; kk < 2; kk++) {
            s16x8 af[4], bf[2];
#pragma unroll
            for (int mt = 0; mt < 4; mt++)
                af[mt] = *(const s16x8*)&Al[kk][(wr + mt * 16 + lr) * 32 + quad * 8];
#pragma unroll
            for (int nt = 0; nt < 2; nt++)
                bf[nt] = *(const s16x8*)&Bl[kk][(wc + nt * 16 + lr) * 32 + quad * 8];
#pragma unroll
            for (int mt = 0; mt < 4; mt++)
#pragma unroll
                for (int nt = 0; nt < 2; nt++)
                    acc[mt][nt] = MFMA_BF16(af[mt], bf[nt], acc[mt][nt]);
        }
    }

#pragma unroll
    for (int mt = 0; mt < 4; mt++)
#pragma unroll
        for (int nt = 0; nt < 2; nt++) {
            int   col  = n0 + wc + nt * 16 + lr;
            float bcol = bias[col];
            int   rbase = m0 + wr + mt * 16 + quad * 4;
#pragma unroll
            for (int r = 0; r < 4; r++)
                C[(size_t)(rbase + r) * 1024 + col] = acc[mt][nt][r] + bcol;
        }
}

// ---------------------------------------------------------------------------
// Flash attention v8 FINAL: 32x32 quarter-split, XCD swizzle, conflict-free
// ST=76, chain-free exp2 softmax. 73.6-74.2 µs measured. Five variants
// (reg-prefetch, shfl-P, lagged-PV dbuf, setprio, +raw barriers) all null or
// regressed — do not restructure further.
// ---------------------------------------------------------------------------
__global__ __launch_bounds__(256)
void flash_attn(const unsigned short* __restrict__ Q,
                const unsigned short* __restrict__ K,
                const unsigned short* __restrict__ Vt,
                const float* __restrict__ maskf,
                unsigned short* __restrict__ O)
{
    constexpr int   ST  = 76;
    constexpr float EPS = 9.31322575e-10f;  // 2^-30
    __shared__ __align__(16) unsigned short Kl[64 * ST]; // [key][d]
    __shared__ __align__(16) unsigned short Vl[64 * ST]; // [d][key]
    __shared__ __align__(16) unsigned short Pl[64 * ST]; // [q][key]
    __shared__ float lsq[4][32];

    const int id    = blockIdx.x;
    const int xcd   = id & 7;
    const int local = id >> 3;
    const int pair  = xcd * 4 + (local >> 5);
    const int b     = pair >> 4;
    const int h     = pair & 15;
    const int q0    = (local & 31) * 64;

    const int tid  = threadIdx.x;
    const int lane = tid & 63;
    const int wid  = tid >> 6;
    const int l31  = lane & 31;
    const int hl   = lane >> 5;
    const int qh   = wid & 1;
    const int kh   = wid >> 1;

    const unsigned short* qg =
        Q + (size_t)(b * 2048 + q0 + qh * 32 + l31) * 1024 + h * 64 + hl * 8;
    s16x8 qf[4];
#pragma unroll
    for (int db = 0; db < 4; db++) qf[db] = *(const s16x8*)(qg + db * 16);

    const float  mq  = maskf[b * 2048 + q0 + qh * 32 + l31];
    const float* mkp = maskf + b * 2048;

    const int lk = (tid >> 3) * ST + (tid & 7) * 8;
    const unsigned short* gK = K  + (size_t)(b * 2048 + (tid >> 3)) * 1024 + h * 64 + (tid & 7) * 8;
    const unsigned short* gV = Vt + (size_t)(b * 1024 + h * 64 + (tid >> 3)) * 2048 + (tid & 7) * 8;

    float  lsum = 0.f;
    f32x16 accO = (f32x16){0.f,0.f,0.f,0.f,0.f,0.f,0.f,0.f,
                           0.f,0.f,0.f,0.f,0.f,0.f,0.f,0.f};

    for (int kt = 0; kt < 2048; kt += 64) {
        __syncthreads();
        *(u16x8*)&Kl[lk]           = *(const u16x8*)(gK + (size_t)kt * 1024);
        *(u16x8*)&Kl[lk + 32 * ST] = *(const u16x8*)(gK + (size_t)(kt + 32) * 1024);
        *(u16x8*)&Vl[lk]           = *(const u16x8*)(gV + kt);
        *(u16x8*)&Vl[lk + 32 * ST] = *(const u16x8*)(gV + kt + (size_t)32 * 2048);
        __syncthreads();

        f32x16 st = (f32x16){0.f,0.f,0.f,0.f,0.f,0.f,0.f,0.f,
                             0.f,0.f,0.f,0.f,0.f,0.f,0.f,0.f};
#pragma unroll
        for (int db = 0; db < 4; db++) {
            s16x8 kf = *(const s16x8*)&Kl[(kh * 32 + l31) * ST + db * 16 + hl * 8];
            st = MFMA32(kf, qf[db], st);
        }
#pragma unroll
        for (int rq = 0; rq < 4; rq++) {
            int   kb = 4 * hl + 8 * rq;
            f32x4 m4 = *(const f32x4*)&mkp[kt + kh * 32 + kb];
            unsigned u[4];
#pragma unroll
            for (int r = 0; r < 4; r++) {
                float e = __builtin_amdgcn_exp2f(st[rq * 4 + r]);
                float p = e * (m4[r] * mq) + EPS;
                lsum += p;
                u[r] = __builtin_bit_cast(unsigned, p) + 0x8000u;
            }
            uint2 w;
            w.x = __builtin_amdgcn_perm(u[1], u[0], 0x07060302u);
            w.y = __builtin_amdgcn_perm(u[3], u[2], 0x07060302u);
            *(uint2*)&Pl[(qh * 32 + l31) * ST + kh * 32 + kb] = w;
        }
        __syncthreads();

#pragma unroll
        for (int ks = 0; ks < 4; ks++) {
            s16x8 pf = *(const s16x8*)&Pl[(qh * 32 + l31) * ST + ks * 16 + hl * 8];
            s16x8 vf = *(const s16x8*)&Vl[(kh * 32 + l31) * ST + ks * 16 + hl * 8];
            accO = MFMA32(pf, vf, accO);
        }
    }

    lsum += __shfl_xor(lsum, 32, 64);
    lsq[wid][l31] = lsum;
    __syncthreads();

#pragma unroll
    for (int rq = 0; rq < 4; rq++) {
        int   qr = 4 * hl + 8 * rq;
        f32x4 lA = *(const f32x4*)&lsq[qh][qr];
        f32x4 lB = *(const f32x4*)&lsq[qh + 2][qr];
#pragma unroll
        for (int r = 0; r < 4; r++) {
            float val = accO[rq * 4 + r] * __builtin_amdgcn_rcpf(lA[r] + lB[r]);
            O[(size_t)(b * 2048 + q0 + qh * 32 + qr + r) * 1024 + h * 64 +
              kh * 32 + l31] = f2b(val);
        }
    }
}

// ---------------------------------------------------------------------------
extern "C" void kernel_launch(void* const* d_in, const int* in_sizes, int n_in,
                              void* d_out, int out_size, void* d_ws, size_t ws_size,
                              hipStream_t stream)
{
    const float* query = (const float*)d_in[0];
    const float* key_  = (const float*)d_in[1];
    const float* value = (const float*)d_in[2];
    const int*   mask  = (const int*)d_in[3];
    const float* Wq    = (const float*)d_in[4];
    const float* bq    = (const float*)d_in[5];
    const float* Wk    = (const float*)d_in[6];
    const float* bk    = (const float*)d_in[7];
    const float* Wv    = (const float*)d_in[8];
    const float* bv    = (const float*)d_in[9];
    const float* Wo    = (const float*)d_in[10];
    const float* bo    = (const float*)d_in[11];
    float* out = (float*)d_out;

    unsigned short* cvt = (unsigned short*)d_ws;
    unsigned short* Aq  = cvt;
    unsigned short* Ak  = cvt + M4;
    unsigned short* Av  = cvt + 2 * M4;
    unsigned short* Wqb = cvt + 3 * M4;
    unsigned short* Wkb = Wqb + M1;
    unsigned short* Wvb = Wkb + M1;
    unsigned short* Wob = Wvb + M1;
    unsigned short* Qb  = Wob + M1;
    unsigned short* Kb  = Qb + M4;
    unsigned short* Vt  = Kb + M4;
    unsigned short* Ab  = Vt + M4;
    float*          mkf = (float*)(Ab + M4);

    CvtArgs ca;
    ca.src[0] = query; ca.src[1] = key_; ca.src[2] = value;
    ca.src[3] = Wq; ca.src[4] = Wk; ca.src[5] = Wv; ca.src[6] = Wo;
    ca.dst = cvt; ca.mask = mask; ca.maskf = mkf;
    cvt_bf16<<<dim3(8193), 256, 0, stream>>>(ca);

    GArgs ga;
    ga.A[0] = Aq;  ga.A[1] = Ak;  ga.A[2] = Av;
    ga.W[0] = Wqb; ga.W[1] = Wkb; ga.W[2] = Wvb;
    ga.bias[0] = bq; ga.bias[1] = bk; ga.bias[2] = bv;
    ga.C[0] = Qb; ga.C[1] = Kb; ga.C[2] = Vt;
    proj_gemm<<<dim3(768), 256, 0, stream>>>(ga);

    flash_attn<<<dim3(1024), 256, 0, stream>>>(Qb, Kb, Vt, mkf, Ab);
    out_gemm<<<dim3(512), 256, 0, stream>>>(Ab, Wob, bo, out);
}

// Round 9
// 234.442 us; speedup vs baseline: 1.0905x; 1.0905x over previous
//
#include <hip/hip_runtime.h>

typedef __attribute__((ext_vector_type(4)))  float          f32x4;
typedef __attribute__((ext_vector_type(16))) float          f32x16;
typedef __attribute__((ext_vector_type(8)))  short          s16x8;
typedef __attribute__((ext_vector_type(4)))  unsigned short u16x4;
typedef __attribute__((ext_vector_type(8)))  unsigned short u16x8;

#define MFMA_BF16(a, b, c) __builtin_amdgcn_mfma_f32_16x16x32_bf16((a), (b), (c), 0, 0, 0)
#define MFMA32(a, b, c)    __builtin_amdgcn_mfma_f32_32x32x16_bf16((a), (b), (c), 0, 0, 0)

static constexpr int Bb = 2, Ss = 2048, Ee = 1024, Hh = 16, Dd = 64;
static constexpr size_t M4 = 4u * 1024 * 1024;
static constexpr size_t M1 = 1024 * 1024;

__device__ __forceinline__ unsigned short f2b(float f) {
    unsigned u = __builtin_bit_cast(unsigned, f);
    u += 0x7fffu + ((u >> 16) & 1u);
    return (unsigned short)(u >> 16);
}

__device__ __forceinline__ void gld_lds16(const unsigned short* g, unsigned short* l) {
    __builtin_amdgcn_global_load_lds(
        (const __attribute__((address_space(1))) unsigned int*)g,
        (__attribute__((address_space(3))) unsigned int*)l, 16, 0, 0);
}

// ---------------------------------------------------------------------------
// Convert fp32 inputs to bf16 workspace + mask -> float array. (FROZEN)
// ---------------------------------------------------------------------------
struct CvtArgs { const float* src[7]; unsigned short* dst;
                 const int* mask; float* maskf; };

__global__ __launch_bounds__(256) void cvt_bf16(CvtArgs a)
{
    if (blockIdx.x == 8192) { // mask -> float (4096 elems)
#pragma unroll
        for (int j = 0; j < 16; j++) {
            int idx = threadIdx.x + j * 256;
            a.maskf[idx] = a.mask[idx] ? 1.f : 0.f;
        }
        return;
    }
    size_t i = ((size_t)blockIdx.x * 256 + threadIdx.x) * 8;
    int seg; size_t off;
    if (i < 3 * M4) { seg = (int)(i / M4);     off = i % M4; }
    else            { size_t j = i - 3 * M4;
                      seg = 3 + (int)(j / M1); off = j % M1; }
    const float* s = a.src[seg] + off;
    f32x4 x0 = *(const f32x4*)s;
    f32x4 x1 = *(const f32x4*)(s + 4);
    u16x8 o = (u16x8){f2b(x0[0]), f2b(x0[1]), f2b(x0[2]), f2b(x0[3]),
                      f2b(x1[0]), f2b(x1[1]), f2b(x1[2]), f2b(x1[3])};
    *(u16x8*)(a.dst + i) = o;
}

// ---------------------------------------------------------------------------
// bf16 GEMM body, 128x128 tile, BK=32 (R4 structure — FINAL. Measured
// regressions: 2-phase dbuf +33 µs, BK=64 two-half +21 µs. In this K=1024
// L2-resident regime, inter-block TLP already covers the staging drain;
// in-wave pipelining only adds LDS/codegen cost.)
// OUT_MODE: 1 bf16 [m][n]; 2 bf16 V-transposed; 3 bf16 scaled by
// 0.125*log2(e) (Q path: folds attn scale + exp->exp2 conversion).
// ---------------------------------------------------------------------------
template <int OUT_MODE>
__device__ __forceinline__ void gemm_bf16_body(const unsigned short* __restrict__ A,
                                               const unsigned short* __restrict__ W,
                                               const float* __restrict__ bias,
                                               void* __restrict__ Cv,
                                               int m0, int n0)
{
    __shared__ __align__(16) unsigned short Al[128 * 32];
    __shared__ __align__(16) unsigned short Bl[128 * 32];

    const int tid  = threadIdx.x;
    const int lane = tid & 63;
    const int wid  = tid >> 6;
    const int quad = lane >> 4;
    const int lr   = lane & 15;
    const int wr   = (wid >> 1) * 64;
    const int wc   = (wid & 1) * 64;

    const int srow = wid * 32 + (lane >> 2);
    const int sk8  = (lane & 3) * 8;
    const unsigned short* gA = A + (size_t)(m0 + srow) * 1024 + sk8;
    const unsigned short* gW = W + (size_t)(n0 + srow) * 1024 + sk8;
    unsigned short* lA = &Al[wid * 1024];
    unsigned short* lW = &Bl[wid * 1024];

    f32x4 acc[4][4];
#pragma unroll
    for (int i = 0; i < 4; i++)
#pragma unroll
        for (int j = 0; j < 4; j++) acc[i][j] = (f32x4){0.f, 0.f, 0.f, 0.f};

    for (int ks = 0; ks < 1024; ks += 32) {
        __syncthreads();
        gld_lds16(gA + ks,              lA);
        gld_lds16(gA + ks + 16 * 1024,  lA + 512);
        gld_lds16(gW + ks,              lW);
        gld_lds16(gW + ks + 16 * 1024,  lW + 512);
        __syncthreads();

        s16x8 af[4], bf[4];
#pragma unroll
        for (int t = 0; t < 4; t++) {
            af[t] = *(const s16x8*)&Al[(wr + t * 16 + lr) * 32 + quad * 8];
            bf[t] = *(const s16x8*)&Bl[(wc + t * 16 + lr) * 32 + quad * 8];
        }
#pragma unroll
        for (int mt = 0; mt < 4; mt++)
#pragma unroll
            for (int nt = 0; nt < 4; nt++)
                acc[mt][nt] = MFMA_BF16(af[mt], bf[nt], acc[mt][nt]);
    }

#pragma unroll
    for (int mt = 0; mt < 4; mt++)
#pragma unroll
        for (int nt = 0; nt < 4; nt++) {
            int   col  = n0 + wc + nt * 16 + lr;
            float bcol = bias[col];
            int   rbase = m0 + wr + mt * 16 + quad * 4;
            if (OUT_MODE == 2) {
                int bb = rbase >> 11, s = rbase & 2047;
                u16x4 pk;
#pragma unroll
                for (int r = 0; r < 4; r++) pk[r] = f2b(acc[mt][nt][r] + bcol);
                *(u16x4*)&((unsigned short*)Cv)[((size_t)(bb * 1024 + col)) * 2048 + s] = pk;
            } else {
#pragma unroll
                for (int r = 0; r < 4; r++) {
                    float v = acc[mt][nt][r] + bcol;
                    if (OUT_MODE == 3) v *= 0.180336884f; // 0.125 * log2(e)
                    ((unsigned short*)Cv)[(size_t)(rbase + r) * 1024 + col] = f2b(v);
                }
            }
        }
}

struct GArgs {
    const unsigned short* A[3];
    const unsigned short* W[3];
    const float* bias[3];
    unsigned short* C[3];
};

// XCD-band swizzle: 1D grid 768. xcd = id&7 owns a 512-row A-band for ALL
// n-tiles and all z; dispatch rounds (32 blocks/XCD each) serialize z, so the
// per-XCD L2 working set is 1 MB A-band + 2 MB W = 3 MB < 4 MiB.
__global__ __launch_bounds__(256) void proj_gemm(GArgs ga)
{
    const int id  = blockIdx.x;
    const int xcd = id & 7;
    const int t   = id >> 3;        // 0..95
    const int z   = t >> 5;         // one z per dispatch round
    const int tt  = t & 31;
    const int n0  = (tt & 7) * 128;
    const int m0  = (xcd * 4 + (tt >> 3)) * 128;

    if (z == 2)      gemm_bf16_body<2>(ga.A[2], ga.W[2], ga.bias[2], ga.C[2], m0, n0);
    else if (z == 1) gemm_bf16_body<1>(ga.A[1], ga.W[1], ga.bias[1], ga.C[1], m0, n0);
    else             gemm_bf16_body<3>(ga.A[0], ga.W[0], ga.bias[0], ga.C[0], m0, n0);
}

// ---------------------------------------------------------------------------
// out GEMM: 128x64 tiles -> grid 512 (2 blocks/CU), XCD band swizzle.
// R4 structure — FINAL.
// ---------------------------------------------------------------------------
__global__ __launch_bounds__(256)
void out_gemm(const unsigned short* __restrict__ A,
              const unsigned short* __restrict__ W,
              const float* __restrict__ bias,
              float* __restrict__ C)
{
    __shared__ __align__(16) unsigned short Al[128 * 32];
    __shared__ __align__(16) unsigned short Bl[64 * 32];

    const int id  = blockIdx.x;
    const int xcd = id & 7;
    const int t   = id >> 3;            // 0..63
    const int n0  = (t & 15) * 64;
    const int m0  = (xcd * 4 + (t >> 4)) * 128;

    const int tid  = threadIdx.x;
    const int lane = tid & 63;
    const int wid  = tid >> 6;
    const int quad = lane >> 4;
    const int lr   = lane & 15;
    const int wr   = (wid >> 1) * 64;
    const int wc   = (wid & 1) * 32;

    const int srowA = wid * 32 + (lane >> 2);
    const int srowW = wid * 16 + (lane >> 2);
    const int sk8   = (lane & 3) * 8;
    const unsigned short* gA = A + (size_t)(m0 + srowA) * 1024 + sk8;
    const unsigned short* gW = W + (size_t)(n0 + srowW) * 1024 + sk8;
    unsigned short* lA = &Al[wid * 1024];
    unsigned short* lW = &Bl[wid * 512];

    f32x4 acc[4][2];
#pragma unroll
    for (int i = 0; i < 4; i++)
#pragma unroll
        for (int j = 0; j < 2; j++) acc[i][j] = (f32x4){0.f, 0.f, 0.f, 0.f};

    for (int ks = 0; ks < 1024; ks += 32) {
        __syncthreads();
        gld_lds16(gA + ks,              lA);
        gld_lds16(gA + ks + 16 * 1024,  lA + 512);
        gld_lds16(gW + ks,              lW);
        __syncthreads();

        s16x8 af[4], bf[2];
#pragma unroll
        for (int mt = 0; mt < 4; mt++)
            af[mt] = *(const s16x8*)&Al[(wr + mt * 16 + lr) * 32 + quad * 8];
#pragma unroll
        for (int nt = 0; nt < 2; nt++)
            bf[nt] = *(const s16x8*)&Bl[(wc + nt * 16 + lr) * 32 + quad * 8];
#pragma unroll
        for (int mt = 0; mt < 4; mt++)
#pragma unroll
            for (int nt = 0; nt < 2; nt++)
                acc[mt][nt] = MFMA_BF16(af[mt], bf[nt], acc[mt][nt]);
    }

#pragma unroll
    for (int mt = 0; mt < 4; mt++)
#pragma unroll
        for (int nt = 0; nt < 2; nt++) {
            int   col  = n0 + wc + nt * 16 + lr;
            float bcol = bias[col];
            int   rbase = m0 + wr + mt * 16 + quad * 4;
#pragma unroll
            for (int r = 0; r < 4; r++)
                C[(size_t)(rbase + r) * 1024 + col] = acc[mt][nt][r] + bcol;
        }
}

// ---------------------------------------------------------------------------
// Flash attention v8 FINAL: 32x32 quarter-split, XCD swizzle, conflict-free
// ST=76, chain-free exp2 softmax. 73.6-74.2 µs measured. Five variants
// (reg-prefetch, shfl-P, lagged-PV dbuf, setprio, raw barriers) all null or
// regressed — do not restructure.
// ---------------------------------------------------------------------------
__global__ __launch_bounds__(256)
void flash_attn(const unsigned short* __restrict__ Q,
                const unsigned short* __restrict__ K,
                const unsigned short* __restrict__ Vt,
                const float* __restrict__ maskf,
                unsigned short* __restrict__ O)
{
    constexpr int   ST  = 76;
    constexpr float EPS = 9.31322575e-10f;  // 2^-30
    __shared__ __align__(16) unsigned short Kl[64 * ST]; // [key][d]
    __shared__ __align__(16) unsigned short Vl[64 * ST]; // [d][key]
    __shared__ __align__(16) unsigned short Pl[64 * ST]; // [q][key]
    __shared__ float lsq[4][32];

    const int id    = blockIdx.x;
    const int xcd   = id & 7;
    const int local = id >> 3;
    const int pair  = xcd * 4 + (local >> 5);
    const int b     = pair >> 4;
    const int h     = pair & 15;
    const int q0    = (local & 31) * 64;

    const int tid  = threadIdx.x;
    const int lane = tid & 63;
    const int wid  = tid >> 6;
    const int l31  = lane & 31;
    const int hl   = lane >> 5;
    const int qh   = wid & 1;
    const int kh   = wid >> 1;

    const unsigned short* qg =
        Q + (size_t)(b * 2048 + q0 + qh * 32 + l31) * 1024 + h * 64 + hl * 8;
    s16x8 qf[4];
#pragma unroll
    for (int db = 0; db < 4; db++) qf[db] = *(const s16x8*)(qg + db * 16);

    const float  mq  = maskf[b * 2048 + q0 + qh * 32 + l31];
    const float* mkp = maskf + b * 2048;

    const int lk = (tid >> 3) * ST + (tid & 7) * 8;
    const unsigned short* gK = K  + (size_t)(b * 2048 + (tid >> 3)) * 1024 + h * 64 + (tid & 7) * 8;
    const unsigned short* gV = Vt + (size_t)(b * 1024 + h * 64 + (tid >> 3)) * 2048 + (tid & 7) * 8;

    float  lsum = 0.f;
    f32x16 accO = (f32x16){0.f,0.f,0.f,0.f,0.f,0.f,0.f,0.f,
                           0.f,0.f,0.f,0.f,0.f,0.f,0.f,0.f};

    for (int kt = 0; kt < 2048; kt += 64) {
        __syncthreads();
        *(u16x8*)&Kl[lk]           = *(const u16x8*)(gK + (size_t)kt * 1024);
        *(u16x8*)&Kl[lk + 32 * ST] = *(const u16x8*)(gK + (size_t)(kt + 32) * 1024);
        *(u16x8*)&Vl[lk]           = *(const u16x8*)(gV + kt);
        *(u16x8*)&Vl[lk + 32 * ST] = *(const u16x8*)(gV + kt + (size_t)32 * 2048);
        __syncthreads();

        f32x16 st = (f32x16){0.f,0.f,0.f,0.f,0.f,0.f,0.f,0.f,
                             0.f,0.f,0.f,0.f,0.f,0.f,0.f,0.f};
#pragma unroll
        for (int db = 0; db < 4; db++) {
            s16x8 kf = *(const s16x8*)&Kl[(kh * 32 + l31) * ST + db * 16 + hl * 8];
            st = MFMA32(kf, qf[db], st);
        }
#pragma unroll
        for (int rq = 0; rq < 4; rq++) {
            int   kb = 4 * hl + 8 * rq;
            f32x4 m4 = *(const f32x4*)&mkp[kt + kh * 32 + kb];
            unsigned u[4];
#pragma unroll
            for (int r = 0; r < 4; r++) {
                float e = __builtin_amdgcn_exp2f(st[rq * 4 + r]);
                float p = e * (m4[r] * mq) + EPS;
                lsum += p;
                u[r] = __builtin_bit_cast(unsigned, p) + 0x8000u;
            }
            uint2 w;
            w.x = __builtin_amdgcn_perm(u[1], u[0], 0x07060302u);
            w.y = __builtin_amdgcn_perm(u[3], u[2], 0x07060302u);
            *(uint2*)&Pl[(qh * 32 + l31) * ST + kh * 32 + kb] = w;
        }
        __syncthreads();

#pragma unroll
        for (int ks = 0; ks < 4; ks++) {
            s16x8 pf = *(const s16x8*)&Pl[(qh * 32 + l31) * ST + ks * 16 + hl * 8];
            s16x8 vf = *(const s16x8*)&Vl[(kh * 32 + l31) * ST + ks * 16 + hl * 8];
            accO = MFMA32(pf, vf, accO);
        }
    }

    lsum += __shfl_xor(lsum, 32, 64);
    lsq[wid][l31] = lsum;
    __syncthreads();

#pragma unroll
    for (int rq = 0; rq < 4; rq++) {
        int   qr = 4 * hl + 8 * rq;
        f32x4 lA = *(const f32x4*)&lsq[qh][qr];
        f32x4 lB = *(const f32x4*)&lsq[qh + 2][qr];
#pragma unroll
        for (int r = 0; r < 4; r++) {
            float val = accO[rq * 4 + r] * __builtin_amdgcn_rcpf(lA[r] + lB[r]);
            O[(size_t)(b * 2048 + q0 + qh * 32 + qr + r) * 1024 + h * 64 +
              kh * 32 + l31] = f2b(val);
        }
    }
}

// ---------------------------------------------------------------------------
extern "C" void kernel_launch(void* const* d_in, const int* in_sizes, int n_in,
                              void* d_out, int out_size, void* d_ws, size_t ws_size,
                              hipStream_t stream)
{
    const float* query = (const float*)d_in[0];
    const float* key_  = (const float*)d_in[1];
    const float* value = (const float*)d_in[2];
    const int*   mask  = (const int*)d_in[3];
    const float* Wq    = (const float*)d_in[4];
    const float* bq    = (const float*)d_in[5];
    const float* Wk    = (const float*)d_in[6];
    const float* bk    = (const float*)d_in[7];
    const float* Wv    = (const float*)d_in[8];
    const float* bv    = (const float*)d_in[9];
    const float* Wo    = (const float*)d_in[10];
    const float* bo    = (const float*)d_in[11];
    float* out = (float*)d_out;

    unsigned short* cvt = (unsigned short*)d_ws;
    unsigned short* Aq  = cvt;
    unsigned short* Ak  = cvt + M4;
    unsigned short* Av  = cvt + 2 * M4;
    unsigned short* Wqb = cvt + 3 * M4;
    unsigned short* Wkb = Wqb + M1;
    unsigned short* Wvb = Wkb + M1;
    unsigned short* Wob = Wvb + M1;
    unsigned short* Qb  = Wob + M1;
    unsigned short* Kb  = Qb + M4;
    unsigned short* Vt  = Kb + M4;
    unsigned short* Ab  = Vt + M4;
    float*          mkf = (float*)(Ab + M4);

    CvtArgs ca;
    ca.src[0] = query; ca.src[1] = key_; ca.src[2] = value;
    ca.src[3] = Wq; ca.src[4] = Wk; ca.src[5] = Wv; ca.src[6] = Wo;
    ca.dst = cvt; ca.mask = mask; ca.maskf = mkf;
    cvt_bf16<<<dim3(8193), 256, 0, stream>>>(ca);

    GArgs ga;
    ga.A[0] = Aq;  ga.A[1] = Ak;  ga.A[2] = Av;
    ga.W[0] = Wqb; ga.W[1] = Wkb; ga.W[2] = Wvb;
    ga.bias[0] = bq; ga.bias[1] = bk; ga.bias[2] = bv;
    ga.C[0] = Qb; ga.C[1] = Kb; ga.C[2] = Vt;
    proj_gemm<<<dim3(768), 256, 0, stream>>>(ga);

    flash_attn<<<dim3(1024), 256, 0, stream>>>(Qb, Kb, Vt, mkf, Ab);
    out_gemm<<<dim3(512), 256, 0, stream>>>(Ab, Wob, bo, out);
}